// Round 2
// baseline (505.332 us; speedup 1.0000x reference)
//
#include <hip/hip_runtime.h>
#include <hip/hip_bf16.h>
#include <hip/hip_cooperative_groups.h>

// INRformer forward, MI355X gfx950. Inputs f32, labels i32, output f32 (4096x1).
// B=4096, D=128, H=4, HD=32, NC=10. Internal activations bf16 for MFMA.
// Round 9: ONE cooperative kernel (256 blocks x 512 threads, 1 block/CU),
// phases separated by grid.sync():
//   ph0 init (PE/embed + weight cvt + catab) -> ph1 qkv GEMM ->
//   ph2 attention ksplit partials -> ph3 combine (in LDS) + fused tail.
// Removes all kernel boundaries, k_attn_fin, and the attnb global buffer.
// All compute bodies identical to the verified round-7/8 kernels; only the
// work->wave mapping and LDS overlays changed.

namespace cg = cooperative_groups;

typedef __bf16 bf16_t;
typedef __bf16 bf16x8 __attribute__((ext_vector_type(8)));
typedef __bf16 bf16x4 __attribute__((ext_vector_type(4)));
typedef float  f32x4  __attribute__((ext_vector_type(4)));

__device__ __forceinline__ f32x4 mfma16(bf16x8 a, bf16x8 b, f32x4 c) {
  return __builtin_amdgcn_mfma_f32_16x16x32_bf16(a, b, c, 0, 0, 0);
}

struct P {
  const float* coords; const int* labels;
  const float* ce_w;   const float* ce_b;
  const float* sa_in_b; const float* sa_out_b;
  const float* n1g; const float* n1b;
  const float* m1_b1; const float* m1_b2;
  const float* n2g; const float* n2b;
  const float* n3g; const float* n3b;
  const float* m2_b1; const float* m2_b2;
  const float* n4g; const float* n4b;
  const float* fin_w; const float* fin_b;
  // weight-cvt sources (f32)
  const float* s0; const float* s1; const float* s2;
  const float* s3; const float* s4; const float* s5;
  // catab inputs
  const float* emb; const float* wvp; const float* bvp;
  const float* cow; const float* cob;
  // workspace
  float* xf; float* tab; bf16_t* wsb; bf16_t* xb;
  bf16_t* qkvb; bf16_t* vT; bf16_t* opart; float* lpart;
  // converted weights (aliases into wsb)
  const bf16_t* w_sain; const bf16_t* w_saout;
  const bf16_t* w_m1w1; const bf16_t* w_m1w2;
  const bf16_t* w_m2w1; const bf16_t* w_m2w2;
  float* out;
};

// LDS overlay offsets (bytes). Max use = attn phase 72704 B.
#define SM_KBUF(g)  ((g) * 9216)              // [128][36] bf16  x2
#define SM_VBUF(g)  (18432 + (g) * 8704)      // [32][136] bf16  x2
#define SM_PT(wv)   (35840 + (wv) * 4608)     // [2][16][72] bf16 x8 -> 72704
// tail overlay: xs 0..8448 | xsb 8448..12800 | att 12800..17152 |
//               hb 17152..33792 | red 33792..34816 | Ls 34816..35072

__global__ __launch_bounds__(512, 2) void k_fused(P p) {
  cg::grid_group grid = cg::this_grid();
  __shared__ char smem[74240] __attribute__((aligned(16)));

  const int b    = blockIdx.x;      // 0..255
  const int tid  = threadIdx.x;     // 0..511
  const int lane = tid & 63;
  const int wv   = tid >> 6;        // 0..7
  const int l15  = lane & 15;
  const int quad = lane >> 4;
  const f32x4 zero4 = {0.f, 0.f, 0.f, 0.f};

  // ================= phase 0: embed+PE | weight cvt | catab =================
  {
    int c = b * 512 + tid;                 // 0..131071 = 4096 rows x 32 chunks
    int row = c >> 5, d0 = (c & 31) * 4;
    float c0 = p.coords[row * 2 + 0];
    float c1 = p.coords[row * 2 + 1];
    f32x4 xv; bf16x4 xo;
#pragma unroll
    for (int r = 0; r < 4; r++) {
      int d = d0 + r, j = d >> 1;
      float inv = exp2f(-0.20762050593045953f * (float)j);  // 10000^(-2j/128)
      float pe  = (d & 1) ? cosf(c1 * inv) : sinf(c0 * inv);
      float x = c0 * p.ce_w[2 * d] + c1 * p.ce_w[2 * d + 1] + p.ce_b[d] + pe;
      xv[r] = x; xo[r] = (bf16_t)x;
    }
    *(f32x4*)(p.xf + (size_t)row * 128 + d0) = xv;
    *(bf16x4*)(p.xb + (size_t)row * 128 + d0) = xo;

    if (c < 81920) {  // weight f32->bf16, 4 elems/thread
      const float* src; int off;
      if      (c < 12288) { src = p.s0; off = c; }
      else if (c < 16384) { src = p.s1; off = c - 12288; }
      else if (c < 32768) { src = p.s2; off = c - 16384; }
      else if (c < 49152) { src = p.s3; off = c - 32768; }
      else if (c < 65536) { src = p.s4; off = c - 49152; }
      else                { src = p.s5; off = c - 65536; }
      f32x4 v = *(const f32x4*)(src + (size_t)off * 4);
      bf16x4 o = {(bf16_t)v[0], (bf16_t)v[1], (bf16_t)v[2], (bf16_t)v[3]};
      *(bf16x4*)(p.wsb + (size_t)c * 4) = o;
    }

    if (b == 255) {  // catab (block-local barriers are fine)
      float (*embs)[128] = (float(*)[128])smem;
      float (*t1)[128]   = (float(*)[128])(smem + 5120);
      for (int i = tid; i < 1280; i += 512) embs[i >> 7][i & 127] = p.emb[i];
      __syncthreads();
      for (int o = tid; o < 1280; o += 512) {
        int cc = o >> 7, n = o & 127;
        float acc = p.bvp[n];
        const float* wr = p.wvp + n * 128;
        for (int k2 = 0; k2 < 128; k2++) acc += embs[cc][k2] * wr[k2];
        t1[cc][n] = acc;
      }
      __syncthreads();
      for (int o = tid; o < 1280; o += 512) {
        int cc = o >> 7, dd = o & 127;
        float acc = p.cob[dd];
        const float* wr = p.cow + dd * 128;
        for (int n = 0; n < 128; n++) acc += t1[cc][n] * wr[n];
        p.tab[o] = acc;
      }
    }
  }
  __threadfence();
  grid.sync();

  // ================= phase 1: qkv GEMM (M=4096,N=384,K=128) =================
  {
    int W = b * 8 + wv;                    // 0..2047; 1536 tiles of 32x32
    if (W < 1536) {
      int rt = W / 12, ct = W - rt * 12;
      int row0 = rt * 32, col0 = ct * 32;
      const bf16_t* wr0 = p.w_sain + (size_t)(col0 + l15) * 128 + quad * 8;
      const bf16_t* xr0 = p.xb + (size_t)(row0 + l15) * 128 + quad * 8;
      f32x4 acc[2][2];  // [i: col tile][t: row tile]
      for (int i = 0; i < 2; i++)
        for (int t = 0; t < 2; t++) acc[i][t] = zero4;
#pragma unroll
      for (int kk = 0; kk < 128; kk += 32) {
        bf16x8 a0 = *(const bf16x8*)(wr0 + kk);
        bf16x8 a1 = *(const bf16x8*)(wr0 + 16 * 128 + kk);
        bf16x8 b0 = *(const bf16x8*)(xr0 + kk);
        bf16x8 b1 = *(const bf16x8*)(xr0 + 16 * 128 + kk);
        acc[0][0] = mfma16(a0, b0, acc[0][0]);
        acc[0][1] = mfma16(a0, b1, acc[0][1]);
        acc[1][0] = mfma16(a1, b0, acc[1][0]);
        acc[1][1] = mfma16(a1, b1, acc[1][1]);
      }
      f32x4 bv[2];
      bv[0] = *(const f32x4*)(p.sa_in_b + col0 + quad * 4);
      bv[1] = *(const f32x4*)(p.sa_in_b + col0 + 16 + quad * 4);
#pragma unroll
      for (int t = 0; t < 2; t++) {
        int row = row0 + t * 16 + l15;
#pragma unroll
        for (int i = 0; i < 2; i++) {
          int colb = col0 + i * 16 + quad * 4;
          f32x4 v = acc[i][t] + bv[i];
          bf16x4 o = {(bf16_t)v[0], (bf16_t)v[1], (bf16_t)v[2], (bf16_t)v[3]};
          *(bf16x4*)(p.qkvb + (size_t)row * 384 + colb) = o;
          if (colb >= 256) {  // V block: also store transposed
#pragma unroll
            for (int r = 0; r < 4; r++)
              p.vT[(size_t)(colb - 256 + r) * 4096 + row] = (bf16_t)v[r];
          }
        }
      }
    }
  }
  __threadfence();
  grid.sync();

  // ================= phase 2: attention ksplit partials =====================
  // 8 waves = 2 groups of 4; group g iterates j=0,1 over original attn block
  // orig = b*4 + g*2 + j (h=orig&3, ks=(orig>>2)&7, qt=(orig>>5)*4+wl).
  {
    const int g    = wv >> 2;
    const int wl   = wv & 3;
    const int gtid = wl * 64 + lane;   // 0..255 within group
    bf16_t (*kbuf)[36]      = (bf16_t(*)[36])(smem + SM_KBUF(g));
    bf16_t (*vbuf)[136]     = (bf16_t(*)[136])(smem + SM_VBUF(g));
    bf16_t (*ptw)[16][72]   = (bf16_t(*)[16][72])(smem + SM_PT(wv));

    for (int j = 0; j < 2; j++) {
      int orig = b * 4 + g * 2 + j;        // 0..1023
      int h  = orig & 3;
      int ks = (orig >> 2) & 7;
      int qt = (orig >> 5) * 4 + wl;       // 0..127
      int q0 = qt * 32;
      int kb = ks * 512;
      int task = (qt * 8 + ks) * 4 + h;

      // Q frags (B-operand layout), prescaled by 1/sqrt(32)
      bf16x8 qfA, qfB;
      {
        bf16x8 ra = *(const bf16x8*)(p.qkvb + (size_t)(q0 + l15) * 384 + h * 32 + quad * 8);
        bf16x8 rb = *(const bf16x8*)(p.qkvb + (size_t)(q0 + 16 + l15) * 384 + h * 32 + quad * 8);
#pragma unroll
        for (int jj = 0; jj < 8; jj++) {
          qfA[jj] = (bf16_t)((float)ra[jj] * 0.17677669529663687f);
          qfB[jj] = (bf16_t)((float)rb[jj] * 0.17677669529663687f);
        }
      }

      f32x4 oA0 = zero4, oA1 = zero4, oB0 = zero4, oB1 = zero4;
      float laccA = 0.f, laccB = 0.f;

      for (int kk = 0; kk < 512; kk += 128) {
        __syncthreads();  // protect kbuf/vbuf from previous chunk's readers
#pragma unroll
        for (int rep = 0; rep < 2; rep++) {
          int idx = rep * 256 + gtid;      // 0..511
          int krow = idx >> 2, seg = idx & 3;
          bf16x8 t8 = *(const bf16x8*)(p.qkvb + (size_t)(kb + kk + krow) * 384
                                       + 128 + h * 32 + seg * 8);
          *(bf16x8*)&kbuf[krow][seg * 8] = t8;
          int dim = idx >> 4, vseg = idx & 15;
          bf16x8 v8 = *(const bf16x8*)(p.vT + (size_t)(h * 32 + dim) * 4096
                                       + kb + kk + vseg * 8);
          *(bf16x8*)&vbuf[dim][vseg * 8] = v8;
        }
        __syncthreads();

#pragma unroll
        for (int half = 0; half < 2; half++) {
          const int ko = half * 64;
          bf16x8 kf0 = *(const bf16x8*)&kbuf[ko + l15][quad * 8];
          bf16x8 kf1 = *(const bf16x8*)&kbuf[ko + 16 + l15][quad * 8];
          bf16x8 kf2 = *(const bf16x8*)&kbuf[ko + 32 + l15][quad * 8];
          bf16x8 kf3 = *(const bf16x8*)&kbuf[ko + 48 + l15][quad * 8];

          f32x4 sA[4], sB[4];
          sA[0] = mfma16(kf0, qfA, zero4);
          sA[1] = mfma16(kf1, qfA, zero4);
          sA[2] = mfma16(kf2, qfA, zero4);
          sA[3] = mfma16(kf3, qfA, zero4);
          sB[0] = mfma16(kf0, qfB, zero4);
          sB[1] = mfma16(kf1, qfB, zero4);
          sB[2] = mfma16(kf2, qfB, zero4);
          sB[3] = mfma16(kf3, qfB, zero4);

#pragma unroll
          for (int t = 0; t < 4; t++) {
            float a0 = __expf(sA[t][0]), a1 = __expf(sA[t][1]);
            float a2 = __expf(sA[t][2]), a3 = __expf(sA[t][3]);
            laccA += (a0 + a1) + (a2 + a3);
            bf16x4 pa = {(bf16_t)a0, (bf16_t)a1, (bf16_t)a2, (bf16_t)a3};
            *(bf16x4*)&ptw[0][l15][t * 16 + quad * 4] = pa;
            float b0 = __expf(sB[t][0]), b1 = __expf(sB[t][1]);
            float b2 = __expf(sB[t][2]), b3 = __expf(sB[t][3]);
            laccB += (b0 + b1) + (b2 + b3);
            bf16x4 pb = {(bf16_t)b0, (bf16_t)b1, (bf16_t)b2, (bf16_t)b3};
            *(bf16x4*)&ptw[1][l15][t * 16 + quad * 4] = pb;
          }

          bf16x8 pA0 = *(const bf16x8*)&ptw[0][l15][quad * 8];
          bf16x8 pA1 = *(const bf16x8*)&ptw[0][l15][32 + quad * 8];
          bf16x8 pB0 = *(const bf16x8*)&ptw[1][l15][quad * 8];
          bf16x8 pB1 = *(const bf16x8*)&ptw[1][l15][32 + quad * 8];

          bf16x8 v00 = *(const bf16x8*)&vbuf[l15][ko + quad * 8];
          bf16x8 v01 = *(const bf16x8*)&vbuf[16 + l15][ko + quad * 8];
          bf16x8 v10 = *(const bf16x8*)&vbuf[l15][ko + 32 + quad * 8];
          bf16x8 v11 = *(const bf16x8*)&vbuf[16 + l15][ko + 32 + quad * 8];

          oA0 = mfma16(pA0, v00, oA0);
          oA0 = mfma16(pA1, v10, oA0);
          oA1 = mfma16(pA0, v01, oA1);
          oA1 = mfma16(pA1, v11, oA1);
          oB0 = mfma16(pB0, v00, oB0);
          oB0 = mfma16(pB1, v10, oB0);
          oB1 = mfma16(pB0, v01, oB1);
          oB1 = mfma16(pB1, v11, oB1);
        }
      }

      laccA += __shfl_xor(laccA, 16, 64); laccA += __shfl_xor(laccA, 32, 64);
      laccB += __shfl_xor(laccB, 16, 64); laccB += __shfl_xor(laccB, 32, 64);
      if (quad == 0) {
        p.lpart[task * 32 + l15]      = laccA;
        p.lpart[task * 32 + 16 + l15] = laccB;
      }
      size_t ob = (size_t)task * 1024;  // [32 queries][32 dims]
#pragma unroll
      for (int r = 0; r < 4; r++) {
        int qa = quad * 4 + r;
        p.opart[ob + qa * 32 + l15]             = (bf16_t)oA0[r];
        p.opart[ob + qa * 32 + 16 + l15]        = (bf16_t)oA1[r];
        p.opart[ob + (16 + qa) * 32 + l15]      = (bf16_t)oB0[r];
        p.opart[ob + (16 + qa) * 32 + 16 + l15] = (bf16_t)oB1[r];
      }
    }
  }
  __threadfence();
  grid.sync();

  // ============ phase 3+4: ksplit combine (LDS) + fused tail ===============
  {
    float  (*xs)[132]    = (float(*)[132])(smem);
    bf16_t (*xsb)[136]   = (bf16_t(*)[136])(smem + 8448);
    bf16_t (*att)[136]   = (bf16_t(*)[136])(smem + 12800);
    bf16_t (*hb)[520]    = (bf16_t(*)[520])(smem + 17152);
    float  (*red)[16][8] = (float(*)[16][8])(smem + 33792);
    float  (*Ls)[4]      = (float(*)[4])(smem + 34816);

    const int row = b * 16 + l15;
    const int cb1 = wv * 16;          // wave's col slice, N=128 stages
    const int c1  = cb1 + quad * 4;   // lane's 4 cols
    const int cb4 = wv * 64;          // wave's col slice, N=512 stages

    // ---- combine opart/lpart -> att[16][128]
    if (tid < 64) {
      int rr = tid >> 2, hh = tid & 3;
      int q = b * 16 + rr, qt = q >> 5, ql = q & 31;
      float L = 0.f;
#pragma unroll
      for (int ks = 0; ks < 8; ks++) L += p.lpart[((qt * 8 + ks) * 4 + hh) * 32 + ql];
      Ls[rr][hh] = L;
    }
    __syncthreads();
#pragma unroll
    for (int r = 0; r < 4; r++) {
      int idx = r * 512 + tid;        // 0..2047 = 16 rows x 128 dims
      int rr = idx >> 7, d = idx & 127, hh = d >> 5, dd = d & 31;
      int q = b * 16 + rr, qt = q >> 5, ql = q & 31;
      float O = 0.f;
#pragma unroll
      for (int ks = 0; ks < 8; ks++)
        O += (float)p.opart[(size_t)((qt * 8 + ks) * 4 + hh) * 1024 + ql * 32 + dd];
      att[rr][d] = (bf16_t)(O / Ls[rr][hh]);
    }
    __syncthreads();

    // ---- stage 1: attn out-proj + resid + LN1 -> xs/xsb
    {
      f32x4 acc = zero4;
      const bf16_t* ar = p.w_saout + (size_t)(cb1 + l15) * 128 + quad * 8;
#pragma unroll
      for (int kk = 0; kk < 128; kk += 32) {
        bf16x8 bfr = *(const bf16x8*)&att[l15][kk + quad * 8];
        acc = mfma16(*(const bf16x8*)(ar + kk), bfr, acc);
      }
      f32x4 v = acc + *(const f32x4*)(p.sa_out_b + c1)
                    + *(const f32x4*)(p.xf + (size_t)row * 128 + c1);
      float s  = (v[0] + v[1]) + (v[2] + v[3]);
      float sq = (v[0]*v[0] + v[1]*v[1]) + (v[2]*v[2] + v[3]*v[3]);
      s  += __shfl_xor(s, 16, 64);  s  += __shfl_xor(s, 32, 64);
      sq += __shfl_xor(sq, 16, 64); sq += __shfl_xor(sq, 32, 64);
      if (quad == 0) { red[0][l15][wv] = s; red[1][l15][wv] = sq; }
      __syncthreads();
      float S = 0.f, SQ = 0.f;
#pragma unroll
      for (int w2 = 0; w2 < 8; w2++) { S += red[0][l15][w2]; SQ += red[1][l15][w2]; }
      float mean = S * (1.f / 128.f);
      float rstd = rsqrtf(SQ * (1.f / 128.f) - mean * mean + 1e-5f);
      f32x4 y = (v - mean) * rstd * (*(const f32x4*)(p.n1g + c1))
              + *(const f32x4*)(p.n1b + c1);
      *(f32x4*)&xs[l15][c1] = y;
      bf16x4 o = {(bf16_t)y[0], (bf16_t)y[1], (bf16_t)y[2], (bf16_t)y[3]};
      *(bf16x4*)&xsb[l15][c1] = o;
    }
    __syncthreads();

    // ---- stage 2: mlp1 up + GELU -> hb
    {
      f32x4 au[4] = {zero4, zero4, zero4, zero4};
#pragma unroll
      for (int kk = 0; kk < 128; kk += 32) {
        bf16x8 bfr = *(const bf16x8*)&xsb[l15][kk + quad * 8];
#pragma unroll
        for (int i = 0; i < 4; i++) {
          bf16x8 a = *(const bf16x8*)(p.w_m1w1 + (size_t)(cb4 + i * 16 + l15) * 128
                                      + kk + quad * 8);
          au[i] = mfma16(a, bfr, au[i]);
        }
      }
#pragma unroll
      for (int i = 0; i < 4; i++) {
        int c = cb4 + i * 16 + quad * 4;
        f32x4 vv = au[i] + *(const f32x4*)(p.m1_b1 + c);
#pragma unroll
        for (int r = 0; r < 4; r++)
          vv[r] = 0.5f * vv[r] * (1.0f + erff(vv[r] * 0.70710678118654752f));
        bf16x4 o = {(bf16_t)vv[0], (bf16_t)vv[1], (bf16_t)vv[2], (bf16_t)vv[3]};
        *(bf16x4*)&hb[l15][c] = o;
      }
    }
    __syncthreads();

    // ---- stage 3: mlp1 down + resid + LN2, then +tab[label] + LN3 -> xs/xsb
    {
      f32x4 acc = zero4;
      const bf16_t* ar = p.w_m1w2 + (size_t)(cb1 + l15) * 512 + quad * 8;
#pragma unroll 4
      for (int kk = 0; kk < 512; kk += 32) {
        bf16x8 bfr = *(const bf16x8*)&hb[l15][kk + quad * 8];
        acc = mfma16(*(const bf16x8*)(ar + kk), bfr, acc);
      }
      f32x4 v = acc + *(const f32x4*)(p.m1_b2 + c1) + *(const f32x4*)&xs[l15][c1];
      float s  = (v[0] + v[1]) + (v[2] + v[3]);
      float sq = (v[0]*v[0] + v[1]*v[1]) + (v[2]*v[2] + v[3]*v[3]);
      s  += __shfl_xor(s, 16, 64);  s  += __shfl_xor(s, 32, 64);
      sq += __shfl_xor(sq, 16, 64); sq += __shfl_xor(sq, 32, 64);
      if (quad == 0) { red[0][l15][wv] = s; red[1][l15][wv] = sq; }
      __syncthreads();
      float S = 0.f, SQ = 0.f;
#pragma unroll
      for (int w2 = 0; w2 < 8; w2++) { S += red[0][l15][w2]; SQ += red[1][l15][w2]; }
      float mean = S * (1.f / 128.f);
      float rstd = rsqrtf(SQ * (1.f / 128.f) - mean * mean + 1e-5f);
      int lab = p.labels[row];
      f32x4 y = (v - mean) * rstd * (*(const f32x4*)(p.n2g + c1))
              + *(const f32x4*)(p.n2b + c1)
              + *(const f32x4*)(p.tab + (size_t)lab * 128 + c1);
      float s3  = (y[0] + y[1]) + (y[2] + y[3]);
      float sq3 = (y[0]*y[0] + y[1]*y[1]) + (y[2]*y[2] + y[3]*y[3]);
      s3  += __shfl_xor(s3, 16, 64);  s3  += __shfl_xor(s3, 32, 64);
      sq3 += __shfl_xor(sq3, 16, 64); sq3 += __shfl_xor(sq3, 32, 64);
      __syncthreads();  // all LN2 red reads done before rewrite
      if (quad == 0) { red[0][l15][wv] = s3; red[1][l15][wv] = sq3; }
      __syncthreads();
      float S3 = 0.f, SQ3 = 0.f;
#pragma unroll
      for (int w2 = 0; w2 < 8; w2++) { S3 += red[0][l15][w2]; SQ3 += red[1][l15][w2]; }
      float mean3 = S3 * (1.f / 128.f);
      float rstd3 = rsqrtf(SQ3 * (1.f / 128.f) - mean3 * mean3 + 1e-5f);
      f32x4 y3 = (y - mean3) * rstd3 * (*(const f32x4*)(p.n3g + c1))
               + *(const f32x4*)(p.n3b + c1);
      *(f32x4*)&xs[l15][c1] = y3;
      bf16x4 o = {(bf16_t)y3[0], (bf16_t)y3[1], (bf16_t)y3[2], (bf16_t)y3[3]};
      *(bf16x4*)&xsb[l15][c1] = o;
    }
    __syncthreads();

    // ---- stage 4: mlp2 up + GELU -> hb
    {
      f32x4 au[4] = {zero4, zero4, zero4, zero4};
#pragma unroll
      for (int kk = 0; kk < 128; kk += 32) {
        bf16x8 bfr = *(const bf16x8*)&xsb[l15][kk + quad * 8];
#pragma unroll
        for (int i = 0; i < 4; i++) {
          bf16x8 a = *(const bf16x8*)(p.w_m2w1 + (size_t)(cb4 + i * 16 + l15) * 128
                                      + kk + quad * 8);
          au[i] = mfma16(a, bfr, au[i]);
        }
      }
#pragma unroll
      for (int i = 0; i < 4; i++) {
        int c = cb4 + i * 16 + quad * 4;
        f32x4 vv = au[i] + *(const f32x4*)(p.m2_b1 + c);
#pragma unroll
        for (int r = 0; r < 4; r++)
          vv[r] = 0.5f * vv[r] * (1.0f + erff(vv[r] * 0.70710678118654752f));
        bf16x4 o = {(bf16_t)vv[0], (bf16_t)vv[1], (bf16_t)vv[2], (bf16_t)vv[3]};
        *(bf16x4*)&hb[l15][c] = o;
      }
    }
    __syncthreads();

    // ---- stage 5: mlp2 down + resid + LN4 + fin + sigmoid -> out
    {
      f32x4 acc = zero4;
      const bf16_t* ar = p.w_m2w2 + (size_t)(cb1 + l15) * 512 + quad * 8;
#pragma unroll 4
      for (int kk = 0; kk < 512; kk += 32) {
        bf16x8 bfr = *(const bf16x8*)&hb[l15][kk + quad * 8];
        acc = mfma16(*(const bf16x8*)(ar + kk), bfr, acc);
      }
      f32x4 v = acc + *(const f32x4*)(p.m2_b2 + c1) + *(const f32x4*)&xs[l15][c1];
      float s  = (v[0] + v[1]) + (v[2] + v[3]);
      float sq = (v[0]*v[0] + v[1]*v[1]) + (v[2]*v[2] + v[3]*v[3]);
      s  += __shfl_xor(s, 16, 64);  s  += __shfl_xor(s, 32, 64);
      sq += __shfl_xor(sq, 16, 64); sq += __shfl_xor(sq, 32, 64);
      if (quad == 0) { red[0][l15][wv] = s; red[1][l15][wv] = sq; }
      __syncthreads();
      float S = 0.f, SQ = 0.f;
#pragma unroll
      for (int w2 = 0; w2 < 8; w2++) { S += red[0][l15][w2]; SQ += red[1][l15][w2]; }
      float mean = S * (1.f / 128.f);
      float rstd = rsqrtf(SQ * (1.f / 128.f) - mean * mean + 1e-5f);
      f32x4 y = (v - mean) * rstd * (*(const f32x4*)(p.n4g + c1))
              + *(const f32x4*)(p.n4b + c1);
      f32x4 fwv = *(const f32x4*)(p.fin_w + c1);
      float dot = (y[0]*fwv[0] + y[1]*fwv[1]) + (y[2]*fwv[2] + y[3]*fwv[3]);
      dot += __shfl_xor(dot, 16, 64); dot += __shfl_xor(dot, 32, 64);
      __syncthreads();  // LN4 red reads done before rewrite
      if (quad == 0) red[0][l15][wv] = dot;
      __syncthreads();
      if (wv == 0 && quad == 0) {
        float logit = p.fin_b[0];
#pragma unroll
        for (int w2 = 0; w2 < 8; w2++) logit += red[0][l15][w2];
        p.out[row] = 1.0f / (1.0f + expf(-logit));
      }
    }
  }
}

// --------------------------------------------------------------------------
extern "C" void kernel_launch(void* const* d_in, const int* in_sizes, int n_in,
                              void* d_out, int out_size, void* d_ws, size_t ws_size,
                              hipStream_t stream) {
  const float* coords  = (const float*)d_in[0];
  const int*   labels  = (const int*)d_in[1];
  const float* ce_w    = (const float*)d_in[2];
  const float* ce_b    = (const float*)d_in[3];
  const float* emb     = (const float*)d_in[4];
  const float* sa_in_w = (const float*)d_in[5];
  const float* sa_in_b = (const float*)d_in[6];
  const float* sa_out_w= (const float*)d_in[7];
  const float* sa_out_b= (const float*)d_in[8];
  const float* n1_g    = (const float*)d_in[9];
  const float* n1_b    = (const float*)d_in[10];
  const float* m1_w1   = (const float*)d_in[11];
  const float* m1_b1   = (const float*)d_in[12];
  const float* m1_w2   = (const float*)d_in[13];
  const float* m1_b2   = (const float*)d_in[14];
  const float* n2_g    = (const float*)d_in[15];
  const float* n2_b    = (const float*)d_in[16];
  const float* ca_in_w = (const float*)d_in[17];
  const float* ca_in_b = (const float*)d_in[18];
  const float* ca_out_w= (const float*)d_in[19];
  const float* ca_out_b= (const float*)d_in[20];
  const float* n3_g    = (const float*)d_in[21];
  const float* n3_b    = (const float*)d_in[22];
  const float* m2_w1   = (const float*)d_in[23];
  const float* m2_b1   = (const float*)d_in[24];
  const float* m2_w2   = (const float*)d_in[25];
  const float* m2_b2   = (const float*)d_in[26];
  const float* n4_g    = (const float*)d_in[27];
  const float* n4_b    = (const float*)d_in[28];
  const float* fin_w   = (const float*)d_in[29];
  const float* fin_b   = (const float*)d_in[30];

  // workspace layout (bytes, 16B-aligned) — same as round 7/8
  char* w = (char*)d_ws;
  P prm;
  prm.coords = coords; prm.labels = labels;
  prm.ce_w = ce_w; prm.ce_b = ce_b;
  prm.sa_in_b = sa_in_b; prm.sa_out_b = sa_out_b;
  prm.n1g = n1_g; prm.n1b = n1_b;
  prm.m1_b1 = m1_b1; prm.m1_b2 = m1_b2;
  prm.n2g = n2_g; prm.n2b = n2_b;
  prm.n3g = n3_g; prm.n3b = n3_b;
  prm.m2_b1 = m2_b1; prm.m2_b2 = m2_b2;
  prm.n4g = n4_g; prm.n4b = n4_b;
  prm.fin_w = fin_w; prm.fin_b = fin_b;
  prm.s0 = sa_in_w; prm.s1 = sa_out_w; prm.s2 = m1_w1;
  prm.s3 = m1_w2;   prm.s4 = m2_w1;    prm.s5 = m2_w2;
  prm.emb = emb;
  prm.wvp = ca_in_w + 256 * 128; prm.bvp = ca_in_b + 256;
  prm.cow = ca_out_w; prm.cob = ca_out_b;

  prm.xf    = (float*)(w);
  prm.tab   = (float*)(w + 2097152);
  prm.wsb   = (bf16_t*)(w + 2105344);
  prm.xb    = (bf16_t*)(w + 2760704);
  prm.qkvb  = (bf16_t*)(w + 4857856);
  prm.vT    = (bf16_t*)(w + 8003584);
  prm.opart = (bf16_t*)(w + 9052160);   // 8 MB: 4096 tasks x 32q x 32d
  prm.lpart = (float*)(w + 17440768);   // 512 KB: 4096 x 32

  prm.w_sain  = prm.wsb;
  prm.w_saout = prm.wsb + 49152;
  prm.w_m1w1  = prm.wsb + 65536;
  prm.w_m1w2  = prm.wsb + 131072;
  prm.w_m2w1  = prm.wsb + 196608;
  prm.w_m2w2  = prm.wsb + 262144;
  prm.out = (float*)d_out;

  void* args[] = {(void*)&prm};
  hipLaunchCooperativeKernel((const void*)k_fused, dim3(256), dim3(512),
                             args, 0, stream);

  (void)in_sizes; (void)n_in; (void)out_size; (void)ws_size;
}

// Round 3
// 185.699 us; speedup vs baseline: 2.7212x; 2.7212x over previous
//
#include <hip/hip_runtime.h>
#include <hip/hip_bf16.h>

// INRformer forward, MI355X gfx950. Inputs f32, labels i32, output f32 (4096x1).
// B=4096, D=128, H=4, HD=32, NC=10. Internal activations bf16 for MFMA.
// Round 10: revert cooperative mono-kernel (grid.sync + 1-block/CU TLP loss
// regressed 2.6x). Back to round-8 multi-launch structure, minus two costs:
//   - k_attn_fin fused into k_tail (row-local ksplit combine in LDS; the
//     combine code is the verified round-9 phase-3 prologue). attnb removed.
//   - k_init reshaped to 257 blocks x 512 thr with f32x4 embed+PE and
//     weight-cvt overlay (verified round-9 phase-0 numerics).
// qkv GEMM, k_attn, and the 5-stage tail are byte-identical to the passing
// round-8 kernels. 4 launches total.

typedef __bf16 bf16_t;
typedef __bf16 bf16x8 __attribute__((ext_vector_type(8)));
typedef __bf16 bf16x4 __attribute__((ext_vector_type(4)));
typedef float  f32x4  __attribute__((ext_vector_type(4)));

__device__ __forceinline__ f32x4 mfma16(bf16x8 a, bf16x8 b, f32x4 c) {
  return __builtin_amdgcn_mfma_f32_16x16x32_bf16(a, b, c, 0, 0, 0);
}

// --------------------------------------- init: embed+PE | weight cvt | catab
// blocks 0..255: embed+PE (4 elems/thread) with weight-cvt overlay.
// block 256: ca table.
__global__ __launch_bounds__(512) void k_init(const float* __restrict__ coords,
                                              const float* __restrict__ ce_w,
                                              const float* __restrict__ ce_b,
                                              float* __restrict__ xf,
                                              bf16_t* __restrict__ xb,
                                              const float* __restrict__ s0,
                                              const float* __restrict__ s1,
                                              const float* __restrict__ s2,
                                              const float* __restrict__ s3,
                                              const float* __restrict__ s4,
                                              const float* __restrict__ s5,
                                              bf16_t* __restrict__ wdst,
                                              const float* __restrict__ emb,
                                              const float* __restrict__ wvp,
                                              const float* __restrict__ bvp,
                                              const float* __restrict__ cow,
                                              const float* __restrict__ cob,
                                              float* __restrict__ tab) {
  __shared__ float embs[10][128];
  __shared__ float t1[10][128];
  const int bid = blockIdx.x;
  const int tid = threadIdx.x;
  if (bid < 256) {
    int c = bid * 512 + tid;               // 0..131071 = 4096 rows x 32 chunks
    int row = c >> 5, d0 = (c & 31) * 4;
    float c0 = coords[row * 2 + 0];
    float c1 = coords[row * 2 + 1];
    f32x4 xv; bf16x4 xo;
#pragma unroll
    for (int r = 0; r < 4; r++) {
      int d = d0 + r, j = d >> 1;
      float inv = exp2f(-0.20762050593045953f * (float)j);  // 10000^(-2j/128)
      float pe  = (d & 1) ? cosf(c1 * inv) : sinf(c0 * inv);
      float x = c0 * ce_w[2 * d] + c1 * ce_w[2 * d + 1] + ce_b[d] + pe;
      xv[r] = x; xo[r] = (bf16_t)x;
    }
    *(f32x4*)(xf + (size_t)row * 128 + d0) = xv;
    *(bf16x4*)(xb + (size_t)row * 128 + d0) = xo;

    if (c < 81920) {  // weight f32->bf16, 4 elems/thread
      const float* src; int off;
      if      (c < 12288) { src = s0; off = c; }
      else if (c < 16384) { src = s1; off = c - 12288; }
      else if (c < 32768) { src = s2; off = c - 16384; }
      else if (c < 49152) { src = s3; off = c - 32768; }
      else if (c < 65536) { src = s4; off = c - 49152; }
      else                { src = s5; off = c - 65536; }
      f32x4 v = *(const f32x4*)(src + (size_t)off * 4);
      bf16x4 o = {(bf16_t)v[0], (bf16_t)v[1], (bf16_t)v[2], (bf16_t)v[3]};
      *(bf16x4*)(wdst + (size_t)c * 4) = o;
    }
  } else {  // ---- ca table: tab[c] = (emb[c]@wv^T+bv)@ca_out^T+ca_out_b
    for (int i = tid; i < 1280; i += 512) embs[i >> 7][i & 127] = emb[i];
    __syncthreads();
    for (int o = tid; o < 1280; o += 512) {
      int cc = o >> 7, n = o & 127;
      float acc = bvp[n];
      const float* wr = wvp + n * 128;
      for (int k2 = 0; k2 < 128; k2++) acc += embs[cc][k2] * wr[k2];
      t1[cc][n] = acc;
    }
    __syncthreads();
    for (int o = tid; o < 1280; o += 512) {
      int cc = o >> 7, dd = o & 127;
      float acc = cob[dd];
      const float* wr = cow + dd * 128;
      for (int n = 0; n < 128; n++) acc += t1[cc][n] * wr[n];
      tab[o] = acc;
    }
  }
}

// ------------------------------------------------------- qkv MFMA GEMM
__global__ __launch_bounds__(256) void k_gemm_qkv(const bf16_t* __restrict__ X,
                                                  const bf16_t* __restrict__ Wb,
                                                  const float* __restrict__ bias,
                                                  bf16_t* __restrict__ outB,
                                                  bf16_t* __restrict__ vTout) {
  const int tid  = threadIdx.x;
  const int lane = tid & 63;
  const int wv   = tid >> 6;
  const int l15  = lane & 15;
  const int quad = lane >> 4;
  const int xbase = blockIdx.x * 64 + (wv >> 1) * 32;  // output rows
  const int wbase = blockIdx.y * 64 + (wv & 1) * 32;   // output cols

  const bf16_t* wr0 = Wb + (size_t)(wbase + l15) * 128 + quad * 8;
  const bf16_t* xr0 = X  + (size_t)(xbase + l15) * 128 + quad * 8;

  f32x4 acc[2][2];  // [i: col tile][t: row tile]
  const f32x4 zero4 = {0.f, 0.f, 0.f, 0.f};
  for (int i = 0; i < 2; i++)
    for (int t = 0; t < 2; t++) acc[i][t] = zero4;

#pragma unroll
  for (int kk = 0; kk < 128; kk += 32) {
    bf16x8 a0 = *(const bf16x8*)(wr0 + kk);
    bf16x8 a1 = *(const bf16x8*)(wr0 + 16 * 128 + kk);
    bf16x8 b0 = *(const bf16x8*)(xr0 + kk);
    bf16x8 b1 = *(const bf16x8*)(xr0 + 16 * 128 + kk);
    acc[0][0] = mfma16(a0, b0, acc[0][0]);
    acc[0][1] = mfma16(a0, b1, acc[0][1]);
    acc[1][0] = mfma16(a1, b0, acc[1][0]);
    acc[1][1] = mfma16(a1, b1, acc[1][1]);
  }

  f32x4 bv[2];
  bv[0] = *(const f32x4*)(bias + wbase + quad * 4);
  bv[1] = *(const f32x4*)(bias + wbase + 16 + quad * 4);
#pragma unroll
  for (int t = 0; t < 2; t++) {
    int row = xbase + t * 16 + l15;
#pragma unroll
    for (int i = 0; i < 2; i++) {
      int col0 = wbase + i * 16 + quad * 4;
      f32x4 v = acc[i][t] + bv[i];
      bf16x4 o = {(bf16_t)v[0], (bf16_t)v[1], (bf16_t)v[2], (bf16_t)v[3]};
      *(bf16x4*)(outB + (size_t)row * 384 + col0) = o;
      if (col0 >= 256) {  // V block: also store transposed
#pragma unroll
        for (int r = 0; r < 4; r++)
          vTout[(size_t)(col0 - 256 + r) * 4096 + row] = (bf16_t)v[r];
      }
    }
  }
}

// ----------------------------------------- flash-decoding attention partial
// One wave = (head h, 32-query tile qt, 512-key split ks); 4096 wave-tasks.
// Block's 4 waves share (h,ks); K and V^T staged chunk-wise (128 keys) into
// LDS with coalesced 16B/thread copies, fragments via ds_read_b128.
// m=0 softmax (scores tiny). S^T order (mfma16(kf,qf)) -> b64 P-park.
__global__ __launch_bounds__(256, 4) void k_attn(const bf16_t* __restrict__ qkv,
                                                 const bf16_t* __restrict__ vT,
                                                 bf16_t* __restrict__ opart,
                                                 float* __restrict__ lpart) {
  __shared__ bf16_t kbuf[128][36];     // [key-in-chunk][dim] (+4 pad)
  __shared__ bf16_t vbuf[32][136];     // [dim][key-in-chunk] (+8 pad)
  __shared__ bf16_t pt[4][2][16][72];  // per-wave P park (64-key half)

  const int tid  = threadIdx.x;
  const int lane = tid & 63;
  const int wv   = tid >> 6;
  const int l15  = lane & 15;
  const int quad = lane >> 4;
  const int blk  = blockIdx.x;           // 0..1023
  const int h    = blk & 3;
  const int ks   = (blk >> 2) & 7;
  const int qt   = (blk >> 5) * 4 + wv;  // 0..127
  const int q0   = qt * 32;
  const int kb   = ks * 512;
  const int task = (qt * 8 + ks) * 4 + h;

  // Q frags (B-operand layout: query at l15, d at quad*8+j), prescaled
  bf16x8 qfA, qfB;
  {
    bf16x8 ra = *(const bf16x8*)(qkv + (size_t)(q0 + l15) * 384 + h * 32 + quad * 8);
    bf16x8 rb = *(const bf16x8*)(qkv + (size_t)(q0 + 16 + l15) * 384 + h * 32 + quad * 8);
#pragma unroll
    for (int j = 0; j < 8; j++) {
      qfA[j] = (bf16_t)((float)ra[j] * 0.17677669529663687f);
      qfB[j] = (bf16_t)((float)rb[j] * 0.17677669529663687f);
    }
  }

  const f32x4 zero4 = {0.f, 0.f, 0.f, 0.f};
  f32x4 oA0 = zero4, oA1 = zero4, oB0 = zero4, oB1 = zero4;
  float laccA = 0.f, laccB = 0.f;

  for (int kk = 0; kk < 512; kk += 128) {
    __syncthreads();  // protect kbuf/vbuf from previous chunk's readers
    // ---- stage K chunk: 128 rows x 32 dims (64 B/row, 4 x 16B threads/row)
#pragma unroll
    for (int rep = 0; rep < 2; rep++) {
      int idx = rep * 256 + tid;           // 0..511
      int row = idx >> 2, seg = idx & 3;
      bf16x8 t8 = *(const bf16x8*)(qkv + (size_t)(kb + kk + row) * 384
                                   + 128 + h * 32 + seg * 8);
      *(bf16x8*)&kbuf[row][seg * 8] = t8;
      // ---- stage V^T chunk: 32 dims x 128 keys (256 B/row, 16 x 16B/row)
      int dim = idx >> 4, vseg = idx & 15;
      bf16x8 v8 = *(const bf16x8*)(vT + (size_t)(h * 32 + dim) * 4096
                                   + kb + kk + vseg * 8);
      *(bf16x8*)&vbuf[dim][vseg * 8] = v8;
    }
    __syncthreads();

    // ---- two 64-key halves
#pragma unroll
    for (int half = 0; half < 2; half++) {
      const int ko = half * 64;
      bf16x8 kf0 = *(const bf16x8*)&kbuf[ko + l15][quad * 8];
      bf16x8 kf1 = *(const bf16x8*)&kbuf[ko + 16 + l15][quad * 8];
      bf16x8 kf2 = *(const bf16x8*)&kbuf[ko + 32 + l15][quad * 8];
      bf16x8 kf3 = *(const bf16x8*)&kbuf[ko + 48 + l15][quad * 8];

      f32x4 sA[4], sB[4];
      sA[0] = mfma16(kf0, qfA, zero4);
      sA[1] = mfma16(kf1, qfA, zero4);
      sA[2] = mfma16(kf2, qfA, zero4);
      sA[3] = mfma16(kf3, qfA, zero4);
      sB[0] = mfma16(kf0, qfB, zero4);
      sB[1] = mfma16(kf1, qfB, zero4);
      sB[2] = mfma16(kf2, qfB, zero4);
      sB[3] = mfma16(kf3, qfB, zero4);

#pragma unroll
      for (int t = 0; t < 4; t++) {
        float a0 = __expf(sA[t][0]), a1 = __expf(sA[t][1]);
        float a2 = __expf(sA[t][2]), a3 = __expf(sA[t][3]);
        laccA += (a0 + a1) + (a2 + a3);
        bf16x4 pa = {(bf16_t)a0, (bf16_t)a1, (bf16_t)a2, (bf16_t)a3};
        *(bf16x4*)&pt[wv][0][l15][t * 16 + quad * 4] = pa;
        float b0 = __expf(sB[t][0]), b1 = __expf(sB[t][1]);
        float b2 = __expf(sB[t][2]), b3 = __expf(sB[t][3]);
        laccB += (b0 + b1) + (b2 + b3);
        bf16x4 pb = {(bf16_t)b0, (bf16_t)b1, (bf16_t)b2, (bf16_t)b3};
        *(bf16x4*)&pt[wv][1][l15][t * 16 + quad * 4] = pb;
      }

      bf16x8 pA0 = *(const bf16x8*)&pt[wv][0][l15][quad * 8];
      bf16x8 pA1 = *(const bf16x8*)&pt[wv][0][l15][32 + quad * 8];
      bf16x8 pB0 = *(const bf16x8*)&pt[wv][1][l15][quad * 8];
      bf16x8 pB1 = *(const bf16x8*)&pt[wv][1][l15][32 + quad * 8];

      bf16x8 v00 = *(const bf16x8*)&vbuf[l15][ko + quad * 8];
      bf16x8 v01 = *(const bf16x8*)&vbuf[16 + l15][ko + quad * 8];
      bf16x8 v10 = *(const bf16x8*)&vbuf[l15][ko + 32 + quad * 8];
      bf16x8 v11 = *(const bf16x8*)&vbuf[16 + l15][ko + 32 + quad * 8];

      oA0 = mfma16(pA0, v00, oA0);
      oA0 = mfma16(pA1, v10, oA0);
      oA1 = mfma16(pA0, v01, oA1);
      oA1 = mfma16(pA1, v11, oA1);
      oB0 = mfma16(pB0, v00, oB0);
      oB0 = mfma16(pB1, v10, oB0);
      oB1 = mfma16(pB0, v01, oB1);
      oB1 = mfma16(pB1, v11, oB1);
    }
  }

  // l: sum the 4 quad-partials for each query lane
  laccA += __shfl_xor(laccA, 16, 64); laccA += __shfl_xor(laccA, 32, 64);
  laccB += __shfl_xor(laccB, 16, 64); laccB += __shfl_xor(laccB, 32, 64);
  if (quad == 0) {
    lpart[task * 32 + l15]      = laccA;
    lpart[task * 32 + 16 + l15] = laccB;
  }

  size_t ob = (size_t)task * 1024;  // [32 queries][32 dims]
#pragma unroll
  for (int r = 0; r < 4; r++) {
    int qa = quad * 4 + r;
    opart[ob + qa * 32 + l15]             = (bf16_t)oA0[r];
    opart[ob + qa * 32 + 16 + l15]        = (bf16_t)oA1[r];
    opart[ob + (16 + qa) * 32 + l15]      = (bf16_t)oB0[r];
    opart[ob + (16 + qa) * 32 + 16 + l15] = (bf16_t)oB1[r];
  }
}

// --------------------------------------------------------------------------
// Fused tail incl. ksplit combine. 256 blocks x 512 threads (8 waves); each
// block owns 16 rows. Combine opart/lpart -> att in LDS, then:
//   x = LN1(att@Wso^T + bso + xf)
//   x = LN2(x + MLP1(x)); x = LN3(x + tab[label])
//   x = LN4(x + MLP2(x)); out = sigmoid(x . fw + fb)
__global__ __launch_bounds__(512) void k_tail(
    const bf16_t* __restrict__ opart, const float* __restrict__ lpart,
    const float* __restrict__ xf,
    const bf16_t* __restrict__ wso, const float* __restrict__ bso,
    const float* __restrict__ n1g, const float* __restrict__ n1b,
    const bf16_t* __restrict__ w11, const float* __restrict__ b11,
    const bf16_t* __restrict__ w12, const float* __restrict__ b12,
    const float* __restrict__ n2g, const float* __restrict__ n2b,
    const int* __restrict__ labels, const float* __restrict__ tab,
    const float* __restrict__ n3g, const float* __restrict__ n3b,
    const bf16_t* __restrict__ w21, const float* __restrict__ b21,
    const bf16_t* __restrict__ w22, const float* __restrict__ b22,
    const float* __restrict__ n4g, const float* __restrict__ n4b,
    const float* __restrict__ fw, const float* __restrict__ fb,
    float* __restrict__ out) {
  __shared__ float  xs[16][132];    // row state f32 (+4 pad)
  __shared__ bf16_t xsb[16][136];   // row state bf16 (+8 pad)
  __shared__ bf16_t att[16][136];   // combined attention rows (+8 pad)
  __shared__ bf16_t hb[16][520];    // MLP hidden bf16 (+8 pad)
  __shared__ float  red[2][16][8];  // [metric][row][wave]
  __shared__ float  Ls[16][4];      // per-row per-head denominators

  const int b    = blockIdx.x;
  const int tid  = threadIdx.x;
  const int lane = tid & 63;
  const int wv   = tid >> 6;        // 0..7
  const int l15  = lane & 15;
  const int quad = lane >> 4;
  const int row  = b * 16 + l15;
  const int cb1  = wv * 16;         // this wave's col slice, N=128 stages
  const int c1   = cb1 + quad * 4;  // this lane's 4 cols
  const int cb4  = wv * 64;         // this wave's col slice, N=512 stages

  const f32x4 zero4 = {0.f, 0.f, 0.f, 0.f};

  // ---- combine opart/lpart -> att[16][128]
  if (tid < 64) {
    int rr = tid >> 2, hh = tid & 3;
    int q = b * 16 + rr, qt = q >> 5, ql = q & 31;
    float L = 0.f;
#pragma unroll
    for (int ks = 0; ks < 8; ks++) L += lpart[((qt * 8 + ks) * 4 + hh) * 32 + ql];
    Ls[rr][hh] = L;
  }
  __syncthreads();
#pragma unroll
  for (int r = 0; r < 4; r++) {
    int idx = r * 512 + tid;        // 0..2047 = 16 rows x 128 dims
    int rr = idx >> 7, d = idx & 127, hh = d >> 5, dd = d & 31;
    int q = b * 16 + rr, qt = q >> 5, ql = q & 31;
    float O = 0.f;
#pragma unroll
    for (int ks = 0; ks < 8; ks++)
      O += (float)opart[(size_t)((qt * 8 + ks) * 4 + hh) * 1024 + ql * 32 + dd];
    att[rr][d] = (bf16_t)(O / Ls[rr][hh]);
  }
  __syncthreads();

  // ---------------- stage 1: attn out-proj + resid + LN1 -> xs/xsb
  {
    f32x4 acc = zero4;
    const bf16_t* ar = wso + (size_t)(cb1 + l15) * 128 + quad * 8;
#pragma unroll
    for (int kk = 0; kk < 128; kk += 32) {
      bf16x8 bfr = *(const bf16x8*)&att[l15][kk + quad * 8];
      acc = mfma16(*(const bf16x8*)(ar + kk), bfr, acc);
    }
    f32x4 v = acc + *(const f32x4*)(bso + c1)
                  + *(const f32x4*)(xf + (size_t)row * 128 + c1);
    float s  = (v[0] + v[1]) + (v[2] + v[3]);
    float sq = (v[0]*v[0] + v[1]*v[1]) + (v[2]*v[2] + v[3]*v[3]);
    s  += __shfl_xor(s, 16, 64);  s  += __shfl_xor(s, 32, 64);
    sq += __shfl_xor(sq, 16, 64); sq += __shfl_xor(sq, 32, 64);
    if (quad == 0) { red[0][l15][wv] = s; red[1][l15][wv] = sq; }
    __syncthreads();
    float S = 0.f, SQ = 0.f;
#pragma unroll
    for (int w2 = 0; w2 < 8; w2++) { S += red[0][l15][w2]; SQ += red[1][l15][w2]; }
    float mean = S * (1.f / 128.f);
    float rstd = rsqrtf(SQ * (1.f / 128.f) - mean * mean + 1e-5f);
    f32x4 y = (v - mean) * rstd * (*(const f32x4*)(n1g + c1))
            + *(const f32x4*)(n1b + c1);
    *(f32x4*)&xs[l15][c1] = y;
    bf16x4 o = {(bf16_t)y[0], (bf16_t)y[1], (bf16_t)y[2], (bf16_t)y[3]};
    *(bf16x4*)&xsb[l15][c1] = o;
  }
  __syncthreads();

  // ---------------- stage 2: mlp1 up + GELU -> hb
  {
    f32x4 au[4] = {zero4, zero4, zero4, zero4};
#pragma unroll
    for (int kk = 0; kk < 128; kk += 32) {
      bf16x8 bfr = *(const bf16x8*)&xsb[l15][kk + quad * 8];
#pragma unroll
      for (int i = 0; i < 4; i++) {
        bf16x8 a = *(const bf16x8*)(w11 + (size_t)(cb4 + i * 16 + l15) * 128
                                    + kk + quad * 8);
        au[i] = mfma16(a, bfr, au[i]);
      }
    }
#pragma unroll
    for (int i = 0; i < 4; i++) {
      int c = cb4 + i * 16 + quad * 4;
      f32x4 vv = au[i] + *(const f32x4*)(b11 + c);
#pragma unroll
      for (int r = 0; r < 4; r++)
        vv[r] = 0.5f * vv[r] * (1.0f + erff(vv[r] * 0.70710678118654752f));
      bf16x4 o = {(bf16_t)vv[0], (bf16_t)vv[1], (bf16_t)vv[2], (bf16_t)vv[3]};
      *(bf16x4*)&hb[l15][c] = o;
    }
  }
  __syncthreads();

  // ------- stage 3: mlp1 down + resid + LN2, then +tab[label] + LN3 -> xs/xsb
  {
    f32x4 acc = zero4;
    const bf16_t* ar = w12 + (size_t)(cb1 + l15) * 512 + quad * 8;
#pragma unroll 4
    for (int kk = 0; kk < 512; kk += 32) {
      bf16x8 bfr = *(const bf16x8*)&hb[l15][kk + quad * 8];
      acc = mfma16(*(const bf16x8*)(ar + kk), bfr, acc);
    }
    f32x4 v = acc + *(const f32x4*)(b12 + c1) + *(const f32x4*)&xs[l15][c1];
    // LN2
    float s  = (v[0] + v[1]) + (v[2] + v[3]);
    float sq = (v[0]*v[0] + v[1]*v[1]) + (v[2]*v[2] + v[3]*v[3]);
    s  += __shfl_xor(s, 16, 64);  s  += __shfl_xor(s, 32, 64);
    sq += __shfl_xor(sq, 16, 64); sq += __shfl_xor(sq, 32, 64);
    if (quad == 0) { red[0][l15][wv] = s; red[1][l15][wv] = sq; }
    __syncthreads();
    float S = 0.f, SQ = 0.f;
#pragma unroll
    for (int w2 = 0; w2 < 8; w2++) { S += red[0][l15][w2]; SQ += red[1][l15][w2]; }
    float mean = S * (1.f / 128.f);
    float rstd = rsqrtf(SQ * (1.f / 128.f) - mean * mean + 1e-5f);
    int lab = labels[row];
    f32x4 y = (v - mean) * rstd * (*(const f32x4*)(n2g + c1))
            + *(const f32x4*)(n2b + c1)
            + *(const f32x4*)(tab + (size_t)lab * 128 + c1);
    // LN3
    float s3  = (y[0] + y[1]) + (y[2] + y[3]);
    float sq3 = (y[0]*y[0] + y[1]*y[1]) + (y[2]*y[2] + y[3]*y[3]);
    s3  += __shfl_xor(s3, 16, 64);  s3  += __shfl_xor(s3, 32, 64);
    sq3 += __shfl_xor(sq3, 16, 64); sq3 += __shfl_xor(sq3, 32, 64);
    __syncthreads();  // all LN2 red reads done before rewrite
    if (quad == 0) { red[0][l15][wv] = s3; red[1][l15][wv] = sq3; }
    __syncthreads();
    float S3 = 0.f, SQ3 = 0.f;
#pragma unroll
    for (int w2 = 0; w2 < 8; w2++) { S3 += red[0][l15][w2]; SQ3 += red[1][l15][w2]; }
    float mean3 = S3 * (1.f / 128.f);
    float rstd3 = rsqrtf(SQ3 * (1.f / 128.f) - mean3 * mean3 + 1e-5f);
    f32x4 y3 = (y - mean3) * rstd3 * (*(const f32x4*)(n3g + c1))
             + *(const f32x4*)(n3b + c1);
    *(f32x4*)&xs[l15][c1] = y3;
    bf16x4 o = {(bf16_t)y3[0], (bf16_t)y3[1], (bf16_t)y3[2], (bf16_t)y3[3]};
    *(bf16x4*)&xsb[l15][c1] = o;
  }
  __syncthreads();

  // ---------------- stage 4: mlp2 up + GELU -> hb
  {
    f32x4 au[4] = {zero4, zero4, zero4, zero4};
#pragma unroll
    for (int kk = 0; kk < 128; kk += 32) {
      bf16x8 bfr = *(const bf16x8*)&xsb[l15][kk + quad * 8];
#pragma unroll
      for (int i = 0; i < 4; i++) {
        bf16x8 a = *(const bf16x8*)(w21 + (size_t)(cb4 + i * 16 + l15) * 128
                                    + kk + quad * 8);
        au[i] = mfma16(a, bfr, au[i]);
      }
    }
#pragma unroll
    for (int i = 0; i < 4; i++) {
      int c = cb4 + i * 16 + quad * 4;
      f32x4 vv = au[i] + *(const f32x4*)(b21 + c);
#pragma unroll
      for (int r = 0; r < 4; r++)
        vv[r] = 0.5f * vv[r] * (1.0f + erff(vv[r] * 0.70710678118654752f));
      bf16x4 o = {(bf16_t)vv[0], (bf16_t)vv[1], (bf16_t)vv[2], (bf16_t)vv[3]};
      *(bf16x4*)&hb[l15][c] = o;
    }
  }
  __syncthreads();

  // ---------------- stage 5: mlp2 down + resid + LN4 + fin + sigmoid -> out
  {
    f32x4 acc = zero4;
    const bf16_t* ar = w22 + (size_t)(cb1 + l15) * 512 + quad * 8;
#pragma unroll 4
    for (int kk = 0; kk < 512; kk += 32) {
      bf16x8 bfr = *(const bf16x8*)&hb[l15][kk + quad * 8];
      acc = mfma16(*(const bf16x8*)(ar + kk), bfr, acc);
    }
    f32x4 v = acc + *(const f32x4*)(b22 + c1) + *(const f32x4*)&xs[l15][c1];
    float s  = (v[0] + v[1]) + (v[2] + v[3]);
    float sq = (v[0]*v[0] + v[1]*v[1]) + (v[2]*v[2] + v[3]*v[3]);
    s  += __shfl_xor(s, 16, 64);  s  += __shfl_xor(s, 32, 64);
    sq += __shfl_xor(sq, 16, 64); sq += __shfl_xor(sq, 32, 64);
    if (quad == 0) { red[0][l15][wv] = s; red[1][l15][wv] = sq; }
    __syncthreads();
    float S = 0.f, SQ = 0.f;
#pragma unroll
    for (int w2 = 0; w2 < 8; w2++) { S += red[0][l15][w2]; SQ += red[1][l15][w2]; }
    float mean = S * (1.f / 128.f);
    float rstd = rsqrtf(SQ * (1.f / 128.f) - mean * mean + 1e-5f);
    f32x4 y = (v - mean) * rstd * (*(const f32x4*)(n4g + c1))
            + *(const f32x4*)(n4b + c1);
    f32x4 fwv = *(const f32x4*)(fw + c1);
    float dot = (y[0]*fwv[0] + y[1]*fwv[1]) + (y[2]*fwv[2] + y[3]*fwv[3]);
    dot += __shfl_xor(dot, 16, 64); dot += __shfl_xor(dot, 32, 64);
    __syncthreads();  // LN4 red reads done before rewrite
    if (quad == 0) red[0][l15][wv] = dot;
    __syncthreads();
    if (wv == 0 && quad == 0) {
      float logit = fb[0];
#pragma unroll
      for (int w2 = 0; w2 < 8; w2++) logit += red[0][l15][w2];
      out[row] = 1.0f / (1.0f + expf(-logit));
    }
  }
}

// --------------------------------------------------------------------------
extern "C" void kernel_launch(void* const* d_in, const int* in_sizes, int n_in,
                              void* d_out, int out_size, void* d_ws, size_t ws_size,
                              hipStream_t stream) {
  const float* coords  = (const float*)d_in[0];
  const int*   labels  = (const int*)d_in[1];
  const float* ce_w    = (const float*)d_in[2];
  const float* ce_b    = (const float*)d_in[3];
  const float* emb     = (const float*)d_in[4];
  const float* sa_in_w = (const float*)d_in[5];
  const float* sa_in_b = (const float*)d_in[6];
  const float* sa_out_w= (const float*)d_in[7];
  const float* sa_out_b= (const float*)d_in[8];
  const float* n1_g    = (const float*)d_in[9];
  const float* n1_b    = (const float*)d_in[10];
  const float* m1_w1   = (const float*)d_in[11];
  const float* m1_b1   = (const float*)d_in[12];
  const float* m1_w2   = (const float*)d_in[13];
  const float* m1_b2   = (const float*)d_in[14];
  const float* n2_g    = (const float*)d_in[15];
  const float* n2_b    = (const float*)d_in[16];
  const float* ca_in_w = (const float*)d_in[17];
  const float* ca_in_b = (const float*)d_in[18];
  const float* ca_out_w= (const float*)d_in[19];
  const float* ca_out_b= (const float*)d_in[20];
  const float* n3_g    = (const float*)d_in[21];
  const float* n3_b    = (const float*)d_in[22];
  const float* m2_w1   = (const float*)d_in[23];
  const float* m2_b1   = (const float*)d_in[24];
  const float* m2_w2   = (const float*)d_in[25];
  const float* m2_b2   = (const float*)d_in[26];
  const float* n4_g    = (const float*)d_in[27];
  const float* n4_b    = (const float*)d_in[28];
  const float* fin_w   = (const float*)d_in[29];
  const float* fin_b   = (const float*)d_in[30];
  float* outp = (float*)d_out;

  // workspace layout (bytes, 16B-aligned); same offsets as round 8
  char* w = (char*)d_ws;
  float*  xf    = (float*)(w);
  float*  tab   = (float*)(w + 2097152);
  bf16_t* wsb   = (bf16_t*)(w + 2105344);
  bf16_t* xb    = (bf16_t*)(w + 2760704);
  bf16_t* qkvb  = (bf16_t*)(w + 4857856);
  bf16_t* vT    = (bf16_t*)(w + 8003584);
  bf16_t* opart = (bf16_t*)(w + 9052160);   // 8 MB: 4096 tasks x 32q x 32d
  float*  lpart = (float*)(w + 17440768);   // 512 KB: 4096 x 32

  bf16_t* w_sain  = wsb;
  bf16_t* w_saout = wsb + 49152;
  bf16_t* w_m1w1  = wsb + 65536;
  bf16_t* w_m1w2  = wsb + 131072;
  bf16_t* w_m2w1  = wsb + 196608;
  bf16_t* w_m2w2  = wsb + 262144;

  // embed + weight cvt + ca table (independent, one kernel)
  k_init<<<257, 512, 0, stream>>>(coords, ce_w, ce_b, xf, xb,
                                  sa_in_w, sa_out_w, m1_w1, m1_w2, m2_w1, m2_w2,
                                  wsb, emb, ca_in_w + 256 * 128, ca_in_b + 256,
                                  ca_out_w, ca_out_b, tab);
  // qkv projection (+ transposed V)
  k_gemm_qkv<<<dim3(64, 6), 256, 0, stream>>>(xb, w_sain, sa_in_b, qkvb, vT);
  // self-attention: ksplit=8 partials
  k_attn<<<1024, 256, 0, stream>>>(qkvb, vT, opart, lpart);
  // fused tail: combine -> out-proj+LN1 -> MLP1 -> LN2+CA+LN3 -> MLP2 ->
  //             LN4+fin+sigmoid
  k_tail<<<256, 512, 0, stream>>>(opart, lpart, xf,
                                  w_saout, sa_out_b, n1_g, n1_b,
                                  w_m1w1, m1_b1, w_m1w2, m1_b2, n2_g, n2_b,
                                  labels, tab, n3_g, n3_b,
                                  w_m2w1, m2_b1, w_m2w2, m2_b2, n4_g, n4_b,
                                  fin_w, fin_b, outp);

  (void)in_sizes; (void)n_in; (void)out_size; (void)ws_size;
}